// Round 7
// baseline (170.211 us; speedup 1.0000x reference)
//
#include <hip/hip_runtime.h>
#include <stdint.h>

#define HH 48
#define WW 48
#define NQ 2304             // 48*48
#define NCH 8               // key chunks (6 columns each)
#define NWT 288             // wave-tiles: 16 bh * 6 qt * 3 waves
#define SCL 0.51011868f     // 8^-0.5 * log2(e)  (folded so softmax = exp2)
#define SHIFT 17.312340491f // 12 * log2(e)      (fixed-shift softmax)

__device__ __forceinline__ float rdl(float v, int l) {
    return __int_as_float(__builtin_amdgcn_readlane(__float_as_int(v), l));
}
__device__ __forceinline__ float dot8(float4 a, float4 b, float4 c, float4 d) {
    return a.x*b.x + a.y*b.y + a.z*b.z + a.w*b.w
         + c.x*d.x + c.y*d.y + c.z*d.z + c.w*d.w;
}

// ---------------------------------------------------------------------------
// attn: 2 queries/lane, 128 q/wave. Keys delivered via v_readlane broadcast:
// lanes 0..47 stage 48 keys' KV (64B each) in VGPRs via coalesced-ish global
// gathers; each key is extracted to SGPRs with readlane (VALU, 4 SIMDs) and
// consumed as the one-SGPR operand of each fma. No LDS pipe (R5 wall), no
// SMEM latency (R6 wall). Chunk = 48 rows x 6 cols -> qw[6]/query in VGPRs,
// qh recomputed per key-row (relh hits 2 cache lines/wave).
// logit = q.k + q.rel_w[x2-x+47] + q.rel_h[y2-y+47]; p = exp2(logit'-SHIFT)
// grid 768 = 16 bh * 6 qt * 8 kc  -> exactly 3 blocks/CU. block = 3 waves.
// ---------------------------------------------------------------------------
__global__ __launch_bounds__(192) void attn_kernel(const float* __restrict__ in,
                                                   const float* __restrict__ relw,
                                                   const float* __restrict__ relh,
                                                   float* __restrict__ P) {
    const int bx = blockIdx.x;
    const int bh = bx / 48;
    const int rem = bx - bh * 48;
    const int qt = rem / NCH;          // 0..5
    const int kc = rem - qt * NCH;     // 0..7
    const int tid = threadIdx.x;
    const int lane = tid & 63;
    const int wv = tid >> 6;           // 0..2
    const int b = bh >> 3, h = bh & 7;

    // ---- this lane's two queries ----
    const int n0 = qt * 384 + wv * 128 + lane;
    const int n1 = n0 + 64;
    const int y0 = n0 / WW, x0 = n0 - y0 * WW;
    const int y1 = n1 / WW, x1 = n1 - y1 * WW;

    const float* qp0 = in + ((size_t)(b * NQ + n0) * 192 + h * 8);
    const float* qp1 = in + ((size_t)(b * NQ + n1) * 192 + h * 8);
    float4 q0a = *(const float4*)qp0, q0b = *(const float4*)(qp0 + 4);
    float4 q1a = *(const float4*)qp1, q1b = *(const float4*)(qp1 + 4);
    q0a.x *= SCL; q0a.y *= SCL; q0a.z *= SCL; q0a.w *= SCL;
    q0b.x *= SCL; q0b.y *= SCL; q0b.z *= SCL; q0b.w *= SCL;
    q1a.x *= SCL; q1a.y *= SCL; q1a.z *= SCL; q1a.w *= SCL;
    q1b.x *= SCL; q1b.y *= SCL; q1b.z *= SCL; q1b.w *= SCL;

    // ---- qw per chunk column ----
    float qw0[6], qw1[6];
#pragma unroll
    for (int c = 0; c < 6; ++c) {
        const int x2 = kc * 6 + c;
        const float* r0 = relw + (x2 - x0 + 47) * 8;
        const float* r1 = relw + (x2 - x1 + 47) * 8;
        qw0[c] = dot8(q0a, *(const float4*)r0, q0b, *(const float4*)(r0 + 4));
        qw1[c] = dot8(q1a, *(const float4*)r1, q1b, *(const float4*)(r1 + 4));
    }

    float l0 = 0.0f, l1 = 0.0f;
    float A0[8] = {0, 0, 0, 0, 0, 0, 0, 0};
    float A1[8] = {0, 0, 0, 0, 0, 0, 0, 0};

    // ---- lane -> staged key within a round (8 rows x 6 cols = 48 keys) ----
    int lr = lane / 6, lc = lane - lr * 6;
    if (lane >= 48) { lr = 7; lc = 5; }          // clamp (unused by readlane)
    const int x2l = kc * 6 + lc;

#pragma unroll 1
    for (int R = 0; R < 6; ++R) {
        // stage this round's 48 keys: y2 = R*8 + lr
        const float* kvp = in + ((size_t)(b * NQ + (R * 8 + lr) * 48 + x2l) * 192
                                 + 64 + h * 8);
        const float4 sk0 = *(const float4*)kvp;
        const float4 sk1 = *(const float4*)(kvp + 4);
        const float4 sv0 = *(const float4*)(kvp + 64);   // V is +64 floats
        const float4 sv1 = *(const float4*)(kvp + 68);

#pragma unroll 1
        for (int row = 0; row < 8; ++row) {
            const int y2 = R * 8 + row;
            const float* rh0 = relh + (y2 - y0 + 47) * 8;
            const float* rh1 = relh + (y2 - y1 + 47) * 8;
            const float qh0 = dot8(q0a, *(const float4*)rh0,
                                   q0b, *(const float4*)(rh0 + 4)) - SHIFT;
            const float qh1 = dot8(q1a, *(const float4*)rh1,
                                   q1b, *(const float4*)(rh1 + 4)) - SHIFT;
#pragma unroll
            for (int c = 0; c < 6; ++c) {
                const int idx = row * 6 + c;     // uniform -> single v_readlane
                const float k0 = rdl(sk0.x, idx), k1 = rdl(sk0.y, idx);
                const float k2 = rdl(sk0.z, idx), k3 = rdl(sk0.w, idx);
                const float k4 = rdl(sk1.x, idx), k5 = rdl(sk1.y, idx);
                const float k6 = rdl(sk1.z, idx), k7 = rdl(sk1.w, idx);
                const float v0 = rdl(sv0.x, idx), v1 = rdl(sv0.y, idx);
                const float v2 = rdl(sv0.z, idx), v3 = rdl(sv0.w, idx);
                const float v4 = rdl(sv1.x, idx), v5 = rdl(sv1.y, idx);
                const float v6 = rdl(sv1.z, idx), v7 = rdl(sv1.w, idx);

                float dt0 = qh0 + qw0[c];
                dt0 = fmaf(q0a.x, k0, dt0); dt0 = fmaf(q0a.y, k1, dt0);
                dt0 = fmaf(q0a.z, k2, dt0); dt0 = fmaf(q0a.w, k3, dt0);
                dt0 = fmaf(q0b.x, k4, dt0); dt0 = fmaf(q0b.y, k5, dt0);
                dt0 = fmaf(q0b.z, k6, dt0); dt0 = fmaf(q0b.w, k7, dt0);
                const float p0 = __builtin_amdgcn_exp2f(dt0);
                l0 += p0;
                A0[0] = fmaf(p0, v0, A0[0]); A0[1] = fmaf(p0, v1, A0[1]);
                A0[2] = fmaf(p0, v2, A0[2]); A0[3] = fmaf(p0, v3, A0[3]);
                A0[4] = fmaf(p0, v4, A0[4]); A0[5] = fmaf(p0, v5, A0[5]);
                A0[6] = fmaf(p0, v6, A0[6]); A0[7] = fmaf(p0, v7, A0[7]);

                float dt1 = qh1 + qw1[c];
                dt1 = fmaf(q1a.x, k0, dt1); dt1 = fmaf(q1a.y, k1, dt1);
                dt1 = fmaf(q1a.z, k2, dt1); dt1 = fmaf(q1a.w, k3, dt1);
                dt1 = fmaf(q1b.x, k4, dt1); dt1 = fmaf(q1b.y, k5, dt1);
                dt1 = fmaf(q1b.z, k6, dt1); dt1 = fmaf(q1b.w, k7, dt1);
                const float p1 = __builtin_amdgcn_exp2f(dt1);
                l1 += p1;
                A1[0] = fmaf(p1, v0, A1[0]); A1[1] = fmaf(p1, v1, A1[1]);
                A1[2] = fmaf(p1, v2, A1[2]); A1[3] = fmaf(p1, v3, A1[3]);
                A1[4] = fmaf(p1, v4, A1[4]); A1[5] = fmaf(p1, v5, A1[5]);
                A1[6] = fmaf(p1, v6, A1[6]); A1[7] = fmaf(p1, v7, A1[7]);
            }
        }
    }

    // ---- store partials: slab per (kc, wave-tile), layout [9][128] ----
    const int wt = (bh * 6 + qt) * 3 + wv;
    float* pb = P + ((size_t)kc * NWT + wt) * 1152;
    pb[lane] = l0;
    pb[64 + lane] = l1;
#pragma unroll
    for (int j = 0; j < 8; ++j) {
        pb[(j + 1) * 128 + lane] = A0[j];
        pb[(j + 1) * 128 + 64 + lane] = A1[j];
    }
}

// ---------------------------------------------------------------------------
// merge: sum 8 chunk-partials per query, normalize, write out[b][n][h*8+j]
// ---------------------------------------------------------------------------
__global__ __launch_bounds__(256) void merge_kernel(const float* __restrict__ P,
                                                    float* __restrict__ out) {
    const int t = blockIdx.x * 256 + threadIdx.x;   // [0, 36864)
    const int wt = t >> 7, lq = t & 127;
    float s[9];
#pragma unroll
    for (int j = 0; j < 9; ++j) s[j] = 0.0f;
#pragma unroll
    for (int kcc = 0; kcc < NCH; ++kcc) {
        const float* pb = P + ((size_t)kcc * NWT + wt) * 1152;
#pragma unroll
        for (int j = 0; j < 9; ++j) s[j] += pb[j * 128 + lq];
    }
    const float inv = 1.0f / s[0];
    const int bh = wt / 18;
    const int r2 = wt - bh * 18;
    const int qtl = r2 / 3, wvl = r2 - qtl * 3;
    const int n = qtl * 384 + wvl * 128 + lq;
    const int b = bh >> 3, h = bh & 7;
    float* op = out + ((size_t)(b * NQ + n) * 64 + h * 8);
    ((float4*)op)[0] = make_float4(s[1] * inv, s[2] * inv, s[3] * inv, s[4] * inv);
    ((float4*)op)[1] = make_float4(s[5] * inv, s[6] * inv, s[7] * inv, s[8] * inv);
}

extern "C" void kernel_launch(void* const* d_in, const int* in_sizes, int n_in,
                              void* d_out, int out_size, void* d_ws, size_t ws_size,
                              hipStream_t stream) {
    const float* in   = (const float*)d_in[0];
    const float* relw = (const float*)d_in[1];
    const float* relh = (const float*)d_in[2];
    float* P   = (float*)d_ws;    // 8 * 288 * 1152 * 4 B = 10.6 MB (proven fit)
    float* out = (float*)d_out;

    attn_kernel<<<768, 192, 0, stream>>>(in, relw, relh, P);
    merge_kernel<<<144, 256, 0, stream>>>(P, out);
}